// Round 1
// baseline (3205.143 us; speedup 1.0000x reference)
//
#include <hip/hip_runtime.h>

#define D_FEAT 128

// ---------------- Kernel 1: init workspace ----------------
// zeros summed[N*128] and deg[N]; sets flag=1
__global__ void init_ws_kernel(float* __restrict__ summed_and_deg, long total,
                               int* __restrict__ flag) {
    long gid = (long)blockIdx.x * blockDim.x + threadIdx.x;
    if (gid == 0) *flag = 1;
    long stride = (long)gridDim.x * blockDim.x;
    for (long i = gid; i < total; i += stride) summed_and_deg[i] = 0.0f;
}

// ---------------- Kernel 2: detect int64 vs int32 edge_index ----------------
// If the buffer is little-endian int64 with values < 2^31, every odd 32-bit
// word is zero. Random values in [0,100000) make a false positive impossible.
__global__ void detect_i64_kernel(const int* __restrict__ ei32, int* __restrict__ flag) {
    int t = threadIdx.x;
    int nonzero = 0;
    for (int i = t; i < 4096; i += 256) {
        if (ei32[2 * i + 1] != 0) nonzero = 1;
    }
    if (nonzero) atomicAnd(flag, 0);
}

// ---------------- Kernel 3: edge scatter (atomic) ----------------
// 32 threads per edge; each thread handles 4 contiguous floats.
__global__ void scatter_kernel(const int* __restrict__ ei, const float4* __restrict__ x4,
                               float* __restrict__ summed, float* __restrict__ deg,
                               const int* __restrict__ flag, int E) {
    int gid = blockIdx.x * blockDim.x + threadIdx.x;
    if (gid >= E * 32) return;
    int e = gid >> 5;
    int c = gid & 31;
    int is64 = *flag;
    int src, dst;
    if (is64) {
        src = ei[2 * e];
        dst = ei[2 * E + 2 * e];
    } else {
        src = ei[e];
        dst = ei[E + e];
    }
    float4 v = x4[src * 32 + c];
    float* o = summed + (long)dst * D_FEAT + c * 4;
    atomicAdd(o + 0, v.x);
    atomicAdd(o + 1, v.y);
    atomicAdd(o + 2, v.z);
    atomicAdd(o + 3, v.w);
    if (c == 0) atomicAdd(deg + dst, 1.0f);
}

// ---------------- Kernel 4: deg -> 1/max(deg,1) ----------------
__global__ void invdeg_kernel(float* __restrict__ deg, int N) {
    int gid = blockIdx.x * blockDim.x + threadIdx.x;
    if (gid < N) deg[gid] = 1.0f / fmaxf(deg[gid], 1.0f);
}

// ---------------- Kernel 5: fused GEMM ----------------
// out[n,o] = sum_k agg[n,k]*Wl[o,k] + sum_k x[n,k]*Wr[o,k] + bl[o]
// Tile: 64 nodes x 128 cols per block of 256 threads; K-chunks of 32.
__global__ __launch_bounds__(256) void gemm_kernel(
    const float* __restrict__ x, const float* __restrict__ summed,
    const float* __restrict__ invdeg, const float* __restrict__ Wl,
    const float* __restrict__ bl, const float* __restrict__ Wr,
    float* __restrict__ out, int N) {
    __shared__ __align__(16) float At[64][33];   // [node][k] pad+1 (2-way conflict: free)
    __shared__ __align__(16) float Bt[32][132];  // [k][col] pad to 16B-aligned rows

    const int t = threadIdx.x;
    const int tx = t & 31;   // col group: cols 4*tx .. 4*tx+3
    const int ty = t >> 5;   // node group: nodes ty*8 .. ty*8+7
    const int node0 = blockIdx.x * 64;

    float acc[8][4];
#pragma unroll
    for (int i = 0; i < 8; ++i)
#pragma unroll
        for (int j = 0; j < 4; ++j) acc[i][j] = 0.0f;

    for (int kc = 0; kc < 8; ++kc) {
        const int k0 = kc * 32;
        // stage A: 64x32, 8 elements per thread, coalesced along k
#pragma unroll
        for (int i = 0; i < 8; ++i) {
            int idx = t + i * 256;
            int r = idx >> 5;        // 0..63
            int kk = idx & 31;
            int node = node0 + r;
            int k = k0 + kk;
            float val = 0.0f;
            if (node < N) {
                if (k < 128)
                    val = summed[(long)node * D_FEAT + k] * invdeg[node];
                else
                    val = x[(long)node * D_FEAT + (k - 128)];
            }
            At[r][kk] = val;
        }
        // stage B: 128x32 transposed into [k][col]
#pragma unroll
        for (int i = 0; i < 16; ++i) {
            int idx = t + i * 256;
            int o = idx >> 5;        // 0..127
            int kk = idx & 31;
            int k = k0 + kk;
            float w = (k < 128) ? Wl[o * 128 + k] : Wr[o * 128 + (k - 128)];
            Bt[kk][o] = w;
        }
        __syncthreads();
#pragma unroll
        for (int kk = 0; kk < 32; ++kk) {
            float4 b = *(const float4*)&Bt[kk][tx * 4];
#pragma unroll
            for (int i = 0; i < 8; ++i) {
                float a = At[ty * 8 + i][kk];
                acc[i][0] += a * b.x;
                acc[i][1] += a * b.y;
                acc[i][2] += a * b.z;
                acc[i][3] += a * b.w;
            }
        }
        __syncthreads();
    }

    float4 bias = ((const float4*)bl)[tx];
#pragma unroll
    for (int i = 0; i < 8; ++i) {
        int node = node0 + ty * 8 + i;
        if (node < N) {
            float4 r;
            r.x = acc[i][0] + bias.x;
            r.y = acc[i][1] + bias.y;
            r.z = acc[i][2] + bias.z;
            r.w = acc[i][3] + bias.w;
            ((float4*)(out + (long)node * D_FEAT))[tx] = r;
        }
    }
}

extern "C" void kernel_launch(void* const* d_in, const int* in_sizes, int n_in,
                              void* d_out, int out_size, void* d_ws, size_t ws_size,
                              hipStream_t stream) {
    const float* x = (const float*)d_in[0];
    const int* ei = (const int*)d_in[1];
    const float* Wl = (const float*)d_in[2];
    const float* bl = (const float*)d_in[3];
    const float* Wr = (const float*)d_in[4];
    float* out = (float*)d_out;

    const int N = in_sizes[0] / D_FEAT;   // 100000
    const int E = in_sizes[1] / 2;        // 1600000

    // ws layout: [flag: 64 floats pad][deg: N floats][summed: N*128 floats]
    int* flag = (int*)d_ws;
    float* deg = (float*)d_ws + 64;
    float* summed = deg + N;

    // 1. init (zeros deg+summed contiguously: they are adjacent)
    long total = (long)N * D_FEAT + N;
    {
        int blocks = 2048;
        init_ws_kernel<<<blocks, 256, 0, stream>>>(deg, total, flag);
    }
    // 2. detect edge_index dtype layout
    detect_i64_kernel<<<1, 256, 0, stream>>>(ei, flag);
    // 3. scatter
    {
        long threads = (long)E * 32;
        int blocks = (int)((threads + 255) / 256);
        scatter_kernel<<<blocks, 256, 0, stream>>>(ei, (const float4*)x, summed, deg, flag, E);
    }
    // 4. invdeg
    invdeg_kernel<<<(N + 255) / 256, 256, 0, stream>>>(deg, N);
    // 5. fused GEMM
    gemm_kernel<<<(N + 63) / 64, 256, 0, stream>>>(x, summed, deg, Wl, bl, Wr, out, N);
}

// Round 2
// 809.103 us; speedup vs baseline: 3.9614x; 3.9614x over previous
//
#include <hip/hip_runtime.h>

#define D_FEAT 128

// ws int layout: [flag:64][deg_i:N][offsets:N+1][cursor:N][partials:512][adj:E]

// ---------------- K0: init ----------------
__global__ void init_kernel(int* __restrict__ deg_i, int N, int* __restrict__ flag) {
    int gid = blockIdx.x * blockDim.x + threadIdx.x;
    if (gid == 0) *flag = 1;
    if (gid < N) deg_i[gid] = 0;
}

// ---------------- K1: detect int64 vs int32 edge_index ----------------
__global__ void detect_i64_kernel(const int* __restrict__ ei32, int* __restrict__ flag) {
    int t = threadIdx.x;
    int nonzero = 0;
    for (int i = t; i < 4096; i += 256) {
        if (ei32[2 * i + 1] != 0) nonzero = 1;
    }
    if (nonzero) atomicAnd(flag, 0);
}

__device__ __forceinline__ void decode_edge(const int* ei, int e, int E, int is64,
                                            int& src, int& dst) {
    if (is64) {
        src = ei[2 * e];
        dst = ei[2 * E + 2 * e];
    } else {
        src = ei[e];
        dst = ei[E + e];
    }
}

// ---------------- K2: degree count ----------------
__global__ void count_kernel(const int* __restrict__ ei, int* __restrict__ deg_i,
                             const int* __restrict__ flag, int E) {
    int e = blockIdx.x * blockDim.x + threadIdx.x;
    if (e >= E) return;
    int is64 = *flag;
    int src, dst;
    decode_edge(ei, e, E, is64, src, dst);
    atomicAdd(&deg_i[dst], 1);
}

// ---------------- K3a: block-local exclusive scan ----------------
__global__ __launch_bounds__(256) void scan1_kernel(const int* __restrict__ deg_i,
                                                    int* __restrict__ offsets,
                                                    int* __restrict__ partials, int N) {
    __shared__ int s[256];
    int t = threadIdx.x;
    int gid = blockIdx.x * 256 + t;
    int v = (gid < N) ? deg_i[gid] : 0;
    s[t] = v;
    __syncthreads();
    for (int off = 1; off < 256; off <<= 1) {
        int add = (t >= off) ? s[t - off] : 0;
        __syncthreads();
        s[t] += add;
        __syncthreads();
    }
    if (gid < N) offsets[gid] = s[t] - v;  // exclusive, chunk-local
    if (t == 255) partials[blockIdx.x] = s[255];
}

// ---------------- K3b: scan partials (single block, 512 threads) ----------------
__global__ __launch_bounds__(512) void scan2_kernel(int* __restrict__ partials, int P,
                                                    int* __restrict__ offsets, int N, int E) {
    __shared__ int s[512];
    int t = threadIdx.x;
    int v = (t < P) ? partials[t] : 0;
    s[t] = v;
    __syncthreads();
    for (int off = 1; off < 512; off <<= 1) {
        int add = (t >= off) ? s[t - off] : 0;
        __syncthreads();
        s[t] += add;
        __syncthreads();
    }
    if (t < P) partials[t] = s[t] - v;  // exclusive
    if (t == 0) offsets[N] = E;
}

// ---------------- K3c: add block offsets, init cursor ----------------
__global__ void scan3_kernel(int* __restrict__ offsets, const int* __restrict__ partials,
                             int* __restrict__ cursor, int N) {
    int gid = blockIdx.x * blockDim.x + threadIdx.x;
    if (gid >= N) return;
    int o = offsets[gid] + partials[blockIdx.x];
    offsets[gid] = o;
    cursor[gid] = o;
}

// ---------------- K4: fill adjacency ----------------
__global__ void fill_kernel(const int* __restrict__ ei, int* __restrict__ cursor,
                            int* __restrict__ adj, const int* __restrict__ flag, int E) {
    int e = blockIdx.x * blockDim.x + threadIdx.x;
    if (e >= E) return;
    int is64 = *flag;
    int src, dst;
    decode_edge(ei, e, E, is64, src, dst);
    int slot = atomicAdd(&cursor[dst], 1);
    adj[slot] = src;
}

// ---------------- K5: gather-reduce (mean fused), one wave per node ----------------
// Writes agg[N][128] into `aggp` (aliases d_out).
__global__ __launch_bounds__(256) void gather_kernel(const float2* __restrict__ x2,
                                                     const int* __restrict__ offsets,
                                                     const int* __restrict__ adj,
                                                     float2* aggp, int N) {
    int wave = threadIdx.x >> 6;                 // 0..3
    int lane = threadIdx.x & 63;
    int n = blockIdx.x * 4 + wave;
    if (n >= N) return;
    int start = offsets[n];
    int end = offsets[n + 1];
    float2 acc = make_float2(0.0f, 0.0f);
    for (int j0 = start; j0 < end; j0 += 64) {
        int myadj = (j0 + lane < end) ? adj[j0 + lane] : 0;
        int cnt = min(64, end - j0);
        for (int tt = 0; tt < cnt; ++tt) {
            int src = __shfl(myadj, tt);
            float2 v = x2[src * 64 + lane];
            acc.x += v.x;
            acc.y += v.y;
        }
    }
    int deg = end - start;
    float invd = 1.0f / (float)max(deg, 1);
    acc.x *= invd;
    acc.y *= invd;
    aggp[(long)n * 64 + lane] = acc;
}

// ---------------- K6: fused GEMM ----------------
// out[n,o] = sum_k agg[n,k]*Wl[o,k] + sum_k x[n,k]*Wr[o,k] + bl[o]
// aggp aliases out: each block reads only the rows it later writes.
__global__ __launch_bounds__(256) void gemm_kernel(
    const float* __restrict__ x, const float* aggp,
    const float* __restrict__ Wl, const float* __restrict__ bl,
    const float* __restrict__ Wr, float* out, int N) {
    __shared__ __align__(16) float At[64][33];
    __shared__ __align__(16) float Bt[32][132];

    const int t = threadIdx.x;
    const int tx = t & 31;
    const int ty = t >> 5;
    const int node0 = blockIdx.x * 64;

    float acc[8][4];
#pragma unroll
    for (int i = 0; i < 8; ++i)
#pragma unroll
        for (int j = 0; j < 4; ++j) acc[i][j] = 0.0f;

    for (int kc = 0; kc < 8; ++kc) {
        const int k0 = kc * 32;
#pragma unroll
        for (int i = 0; i < 8; ++i) {
            int idx = t + i * 256;
            int r = idx >> 5;
            int kk = idx & 31;
            int node = node0 + r;
            int k = k0 + kk;
            float val = 0.0f;
            if (node < N) {
                if (k < 128)
                    val = aggp[(long)node * D_FEAT + k];
                else
                    val = x[(long)node * D_FEAT + (k - 128)];
            }
            At[r][kk] = val;
        }
#pragma unroll
        for (int i = 0; i < 16; ++i) {
            int idx = t + i * 256;
            int o = idx >> 5;
            int kk = idx & 31;
            int k = k0 + kk;
            float w = (k < 128) ? Wl[o * 128 + k] : Wr[o * 128 + (k - 128)];
            Bt[kk][o] = w;
        }
        __syncthreads();
#pragma unroll
        for (int kk = 0; kk < 32; ++kk) {
            float4 b = *(const float4*)&Bt[kk][tx * 4];
#pragma unroll
            for (int i = 0; i < 8; ++i) {
                float a = At[ty * 8 + i][kk];
                acc[i][0] += a * b.x;
                acc[i][1] += a * b.y;
                acc[i][2] += a * b.z;
                acc[i][3] += a * b.w;
            }
        }
        __syncthreads();
    }

    float4 bias = ((const float4*)bl)[tx];
#pragma unroll
    for (int i = 0; i < 8; ++i) {
        int node = node0 + ty * 8 + i;
        if (node < N) {
            float4 r;
            r.x = acc[i][0] + bias.x;
            r.y = acc[i][1] + bias.y;
            r.z = acc[i][2] + bias.z;
            r.w = acc[i][3] + bias.w;
            ((float4*)(out + (long)node * D_FEAT))[tx] = r;
        }
    }
}

extern "C" void kernel_launch(void* const* d_in, const int* in_sizes, int n_in,
                              void* d_out, int out_size, void* d_ws, size_t ws_size,
                              hipStream_t stream) {
    const float* x = (const float*)d_in[0];
    const int* ei = (const int*)d_in[1];
    const float* Wl = (const float*)d_in[2];
    const float* bl = (const float*)d_in[3];
    const float* Wr = (const float*)d_in[4];
    float* out = (float*)d_out;

    const int N = in_sizes[0] / D_FEAT;  // 100000
    const int E = in_sizes[1] / 2;       // 1600000

    int* wsI = (int*)d_ws;
    int* flag = wsI;                 // 64
    int* deg_i = flag + 64;          // N
    int* offsets = deg_i + N;        // N+1
    int* cursor = offsets + N + 1;   // N
    int* partials = cursor + N;      // 512
    int* adj = partials + 512;       // E

    const int P = (N + 255) / 256;   // scan blocks (391 <= 512)

    init_kernel<<<(N + 255) / 256, 256, 0, stream>>>(deg_i, N, flag);
    detect_i64_kernel<<<1, 256, 0, stream>>>(ei, flag);
    count_kernel<<<(E + 255) / 256, 256, 0, stream>>>(ei, deg_i, flag, E);
    scan1_kernel<<<P, 256, 0, stream>>>(deg_i, offsets, partials, N);
    scan2_kernel<<<1, 512, 0, stream>>>(partials, P, offsets, N, E);
    scan3_kernel<<<P, 256, 0, stream>>>(offsets, partials, cursor, N);
    fill_kernel<<<(E + 255) / 256, 256, 0, stream>>>(ei, cursor, adj, flag, E);
    gather_kernel<<<(N + 3) / 4, 256, 0, stream>>>((const float2*)x, offsets, adj,
                                                   (float2*)out, N);
    gemm_kernel<<<(N + 63) / 64, 256, 0, stream>>>(x, out, Wl, bl, Wr, out, N);
}

// Round 3
// 471.334 us; speedup vs baseline: 6.8002x; 1.7166x over previous
//
#include <hip/hip_runtime.h>

#define D_FEAT 128

typedef short bf16x8 __attribute__((ext_vector_type(8)));
typedef float f32x4 __attribute__((ext_vector_type(4)));

__device__ __forceinline__ unsigned short f2bf(float f) {
    unsigned u = __builtin_bit_cast(unsigned, f);
    u += 0x7FFF + ((u >> 16) & 1);   // round-to-nearest-even
    return (unsigned short)(u >> 16);
}

// ws int layout: [flag:64][deg_i:N][offsets:N+1][cursor:N][partials:512][adj:E]
// then (16B aligned): Wc[128*256] bf16, agg_bf16[N*128] bf16

// ---------------- K0: init ----------------
__global__ void init_kernel(int* __restrict__ deg_i, int N, int* __restrict__ flag) {
    int gid = blockIdx.x * blockDim.x + threadIdx.x;
    if (gid == 0) *flag = 1;
    if (gid < N) deg_i[gid] = 0;
}

// ---------------- K1: detect int64 vs int32 edge_index ----------------
__global__ void detect_i64_kernel(const int* __restrict__ ei32, int* __restrict__ flag) {
    int t = threadIdx.x;
    int nonzero = 0;
    for (int i = t; i < 4096; i += 256) {
        if (ei32[2 * i + 1] != 0) nonzero = 1;
    }
    if (nonzero) atomicAnd(flag, 0);
}

__device__ __forceinline__ void decode_edge(const int* ei, int e, int E, int is64,
                                            int& src, int& dst) {
    if (is64) {
        src = ei[2 * e];
        dst = ei[2 * E + 2 * e];
    } else {
        src = ei[e];
        dst = ei[E + e];
    }
}

// ---------------- K2: degree count ----------------
__global__ void count_kernel(const int* __restrict__ ei, int* __restrict__ deg_i,
                             const int* __restrict__ flag, int E) {
    int e = blockIdx.x * blockDim.x + threadIdx.x;
    if (e >= E) return;
    int is64 = *flag;
    int src, dst;
    decode_edge(ei, e, E, is64, src, dst);
    atomicAdd(&deg_i[dst], 1);
}

// ---------------- K3a: block-local exclusive scan ----------------
__global__ __launch_bounds__(256) void scan1_kernel(const int* __restrict__ deg_i,
                                                    int* __restrict__ offsets,
                                                    int* __restrict__ partials, int N) {
    __shared__ int s[256];
    int t = threadIdx.x;
    int gid = blockIdx.x * 256 + t;
    int v = (gid < N) ? deg_i[gid] : 0;
    s[t] = v;
    __syncthreads();
    for (int off = 1; off < 256; off <<= 1) {
        int add = (t >= off) ? s[t - off] : 0;
        __syncthreads();
        s[t] += add;
        __syncthreads();
    }
    if (gid < N) offsets[gid] = s[t] - v;
    if (t == 255) partials[blockIdx.x] = s[255];
}

// ---------------- K3b: scan partials ----------------
__global__ __launch_bounds__(512) void scan2_kernel(int* __restrict__ partials, int P,
                                                    int* __restrict__ offsets, int N, int E) {
    __shared__ int s[512];
    int t = threadIdx.x;
    int v = (t < P) ? partials[t] : 0;
    s[t] = v;
    __syncthreads();
    for (int off = 1; off < 512; off <<= 1) {
        int add = (t >= off) ? s[t - off] : 0;
        __syncthreads();
        s[t] += add;
        __syncthreads();
    }
    if (t < P) partials[t] = s[t] - v;
    if (t == 0) offsets[N] = E;
}

// ---------------- K3c: add block offsets, init cursor ----------------
__global__ void scan3_kernel(int* __restrict__ offsets, const int* __restrict__ partials,
                             int* __restrict__ cursor, int N) {
    int gid = blockIdx.x * blockDim.x + threadIdx.x;
    if (gid >= N) return;
    int o = offsets[gid] + partials[blockIdx.x];
    offsets[gid] = o;
    cursor[gid] = o;
}

// ---------------- K4: fill adjacency ----------------
__global__ void fill_kernel(const int* __restrict__ ei, int* __restrict__ cursor,
                            int* __restrict__ adj, const int* __restrict__ flag, int E) {
    int e = blockIdx.x * blockDim.x + threadIdx.x;
    if (e >= E) return;
    int is64 = *flag;
    int src, dst;
    decode_edge(ei, e, E, is64, src, dst);
    int slot = atomicAdd(&cursor[dst], 1);
    adj[slot] = src;
}

// ---------------- K5: pack [Wl|Wr] -> Wc[n][k] bf16 ----------------
__global__ void wc_kernel(const float* __restrict__ Wl, const float* __restrict__ Wr,
                          unsigned short* __restrict__ Wc) {
    int n = blockIdx.x;       // 0..127
    int k = threadIdx.x;      // 0..255
    float w = (k < 128) ? Wl[n * 128 + k] : Wr[n * 128 + (k - 128)];
    Wc[n * 256 + k] = f2bf(w);
}

// ---------------- K6: gather-reduce (mean fused) -> agg bf16 ----------------
// one wave per node; lane l owns cols 2l,2l+1; writes packed 2xbf16 per lane.
__global__ __launch_bounds__(256) void gather_kernel(const float2* __restrict__ x2,
                                                     const int* __restrict__ offsets,
                                                     const int* __restrict__ adj,
                                                     unsigned int* __restrict__ aggb,
                                                     int N) {
    int wave = threadIdx.x >> 6;
    int lane = threadIdx.x & 63;
    int n = blockIdx.x * 4 + wave;
    if (n >= N) return;
    int start = offsets[n];
    int end = offsets[n + 1];
    float2 acc = make_float2(0.0f, 0.0f);
    for (int j0 = start; j0 < end; j0 += 64) {
        int myadj = (j0 + lane < end) ? adj[j0 + lane] : 0;
        int cnt = min(64, end - j0);
        for (int tt = 0; tt < cnt; ++tt) {
            int src = __shfl(myadj, tt);
            float2 v = x2[src * 64 + lane];
            acc.x += v.x;
            acc.y += v.y;
        }
    }
    int deg = end - start;
    float invd = 1.0f / (float)max(deg, 1);
    acc.x *= invd;
    acc.y *= invd;
    unsigned int packed = (unsigned)f2bf(acc.x) | ((unsigned)f2bf(acc.y) << 16);
    aggb[(long)n * 64 + lane] = packed;
}

// ---------------- K7: MFMA GEMM ----------------
// out[n,c] = sum_k A[n,k] * Wc[c,k] + bl[c], A = [agg_bf16 | bf16(x)], K=256.
// Block: 128 nodes x 128 cols, 4 waves; wave w owns cols [w*32, w*32+32).
__global__ __launch_bounds__(256) void gemm_kernel(
    const float4* __restrict__ x4, const uint4* __restrict__ aggb4,
    const unsigned short* __restrict__ Wc, const float* __restrict__ bl,
    float* __restrict__ out, int N) {
    __shared__ unsigned short As[128 * 40];  // 128 rows x 32 k, stride 40 bf16 (80B)

    const int t = threadIdx.x;
    const int wv = t >> 6;
    const int lane = t & 63;
    const int l15 = lane & 15;
    const int quad = lane >> 4;
    const int node0 = blockIdx.x * 128;

    f32x4 acc[2][8];
#pragma unroll
    for (int nt = 0; nt < 2; ++nt)
#pragma unroll
        for (int mt = 0; mt < 8; ++mt) acc[nt][mt] = (f32x4){0.f, 0.f, 0.f, 0.f};

    for (int kc = 0; kc < 8; ++kc) {
        const int k0 = kc * 32;
        // stage A-tile: 512 units of 8 bf16; 2 per thread
#pragma unroll
        for (int u = 0; u < 2; ++u) {
            int pair = t + u * 256;
            int row = pair >> 2;   // 0..127
            int grp = pair & 3;    // k-subgroup of 8
            int node = node0 + row;
            int k = k0 + grp * 8;
            uint4 val = make_uint4(0u, 0u, 0u, 0u);
            if (node < N) {
                if (k < 128) {
                    val = aggb4[((long)node * 128 + k) >> 3];
                } else {
                    long fidx = ((long)node * 128 + (k - 128)) >> 2;
                    float4 f0 = x4[fidx];
                    float4 f1 = x4[fidx + 1];
                    val.x = (unsigned)f2bf(f0.x) | ((unsigned)f2bf(f0.y) << 16);
                    val.y = (unsigned)f2bf(f0.z) | ((unsigned)f2bf(f0.w) << 16);
                    val.z = (unsigned)f2bf(f1.x) | ((unsigned)f2bf(f1.y) << 16);
                    val.w = (unsigned)f2bf(f1.z) | ((unsigned)f2bf(f1.w) << 16);
                }
            }
            *(uint4*)&As[row * 40 + grp * 8] = val;
        }
        __syncthreads();

        // B fragments straight from global (Wc is L1/L2-resident, shared by all blocks)
        bf16x8 bfrag[2];
#pragma unroll
        for (int nt = 0; nt < 2; ++nt) {
            int n = wv * 32 + nt * 16 + l15;
            bfrag[nt] = *(const bf16x8*)&Wc[n * 256 + k0 + quad * 8];
        }
#pragma unroll
        for (int mt = 0; mt < 8; ++mt) {
            bf16x8 afrag = *(const bf16x8*)&As[(mt * 16 + l15) * 40 + quad * 8];
            acc[0][mt] = __builtin_amdgcn_mfma_f32_16x16x32_bf16(afrag, bfrag[0], acc[0][mt], 0, 0, 0);
            acc[1][mt] = __builtin_amdgcn_mfma_f32_16x16x32_bf16(afrag, bfrag[1], acc[1][mt], 0, 0, 0);
        }
        __syncthreads();
    }

    // epilogue: C/D layout col=lane&15, row=quad*4+reg
#pragma unroll
    for (int nt = 0; nt < 2; ++nt) {
        int col = wv * 32 + nt * 16 + l15;
        float bias = bl[col];
#pragma unroll
        for (int mt = 0; mt < 8; ++mt) {
#pragma unroll
            for (int r = 0; r < 4; ++r) {
                int node = node0 + mt * 16 + quad * 4 + r;
                if (node < N) out[(long)node * 128 + col] = acc[nt][mt][r] + bias;
            }
        }
    }
}

extern "C" void kernel_launch(void* const* d_in, const int* in_sizes, int n_in,
                              void* d_out, int out_size, void* d_ws, size_t ws_size,
                              hipStream_t stream) {
    const float* x = (const float*)d_in[0];
    const int* ei = (const int*)d_in[1];
    const float* Wl = (const float*)d_in[2];
    const float* bl = (const float*)d_in[3];
    const float* Wr = (const float*)d_in[4];
    float* out = (float*)d_out;

    const int N = in_sizes[0] / D_FEAT;  // 100000
    const int E = in_sizes[1] / 2;       // 1600000

    int* wsI = (int*)d_ws;
    int* flag = wsI;                 // 64
    int* deg_i = flag + 64;          // N
    int* offsets = deg_i + N;        // N+1
    int* cursor = offsets + N + 1;   // N
    int* partials = cursor + N;      // 512
    int* adj = partials + 512;       // E
    // align to 16B after int region
    size_t int_words = (size_t)(64 + N + (N + 1) + N + 512 + E);
    int_words = (int_words + 3) & ~(size_t)3;
    unsigned short* Wc = (unsigned short*)(wsI + int_words);   // 128*256 bf16 = 64KB
    unsigned short* aggb = Wc + 128 * 256;                     // N*128 bf16

    const int P = (N + 255) / 256;

    init_kernel<<<(N + 255) / 256, 256, 0, stream>>>(deg_i, N, flag);
    detect_i64_kernel<<<1, 256, 0, stream>>>(ei, flag);
    count_kernel<<<(E + 255) / 256, 256, 0, stream>>>(ei, deg_i, flag, E);
    scan1_kernel<<<P, 256, 0, stream>>>(deg_i, offsets, partials, N);
    scan2_kernel<<<1, 512, 0, stream>>>(partials, P, offsets, N, E);
    scan3_kernel<<<P, 256, 0, stream>>>(offsets, partials, cursor, N);
    fill_kernel<<<(E + 255) / 256, 256, 0, stream>>>(ei, cursor, adj, flag, E);
    wc_kernel<<<128, 256, 0, stream>>>(Wl, Wr, Wc);
    gather_kernel<<<(N + 3) / 4, 256, 0, stream>>>((const float2*)x, offsets, adj,
                                                   (unsigned int*)aggb, N);
    gemm_kernel<<<(N + 127) / 128, 256, 0, stream>>>((const float4*)x, (const uint4*)aggb,
                                                     Wc, bl, out, N);
}